// Round 14
// baseline (175.065 us; speedup 1.0000x reference)
//
#include <hip/hip_runtime.h>
#include <stdint.h>

#define DI __device__ __forceinline__

typedef __attribute__((ext_vector_type(8))) __bf16 bfrag;
typedef __attribute__((ext_vector_type(4))) __bf16 bf16x4;
typedef __attribute__((ext_vector_type(4))) float f32x4;

static constexpr int Bb = 8, Ss = 1024, Dd = 768, Hh = 12, DKk = 64;
static constexpr int Mm = Bb * Ss;

typedef __attribute__((address_space(3))) void lds_void_t;
typedef const __attribute__((address_space(1))) void gvoid_t;

DI void async_load16(const void* g, void* lds) {
    __builtin_amdgcn_global_load_lds((gvoid_t*)(uintptr_t)g,
                                     (lds_void_t*)(uint32_t)(uintptr_t)lds, 16, 0, 0);
}

#if __has_builtin(__builtin_amdgcn_exp2f)
#define EXP2(x) __builtin_amdgcn_exp2f(x)
#else
extern "C" __device__ float __ocml_exp2_f32(float);
#define EXP2(x) __ocml_exp2_f32(x)
#endif

// ---- fp32 -> bf16 convert, all 7 tensors in ONE launch ----
__global__ __launch_bounds__(256) void cvt_k(const float* __restrict__ a0, const float* __restrict__ a1,
                                             const float* __restrict__ a2,
                                             const float* __restrict__ w0, const float* __restrict__ w1,
                                             const float* __restrict__ w2, const float* __restrict__ w3,
                                             __bf16* __restrict__ da0, __bf16* __restrict__ da1,
                                             __bf16* __restrict__ da2,
                                             __bf16* __restrict__ dw0, __bf16* __restrict__ dw1,
                                             __bf16* __restrict__ dw2, __bf16* __restrict__ dw3) {
    const int bid = (int)blockIdx.x;
    const float* s; __bf16* d; int off;
    if (bid < 9216) {
        const int ti = bid / 3072;
        off = (bid % 3072) * 2048;
        s = ti == 0 ? a0 : ti == 1 ? a1 : a2;
        d = ti == 0 ? da0 : ti == 1 ? da1 : da2;
    } else {
        const int b2 = bid - 9216;
        const int ti = b2 / 288;
        off = (b2 % 288) * 2048;
        s = ti == 0 ? w0 : ti == 1 ? w1 : ti == 2 ? w2 : w3;
        d = ti == 0 ? dw0 : ti == 1 ? dw1 : ti == 2 ? dw2 : dw3;
    }
    const int i = off + (int)threadIdx.x * 8;
    f32x4 a = *(const f32x4*)(s + i);
    f32x4 b = *(const f32x4*)(s + i + 4);
    bfrag o;
#pragma unroll
    for (int j = 0; j < 4; ++j) { o[j] = (__bf16)a[j]; o[j + 4] = (__bf16)b[j]; }
    *(bfrag*)(d + i) = o;
}

// ==== GEMM core v4: 128x128 tile, BK=32, B-DIRECT-FROM-GLOBAL. ====
// LDS carries ONLY the A tile (2 x 8KB double buffer): halves per-step LDS-pipe
// bytes (48KB -> 24KB) — r8's plateau was LDS-throughput-bound (MfmaUtil 18%,
// per-block CU-time ~4x MFMA floor, ~ LDS-byte floor).
// B frags live in registers, double-buffered b0/b1 (static names, rule #20),
// prefetched one full K-step ahead; W panel is L2-hot (reused by 64 M-blocks).
// A LDS swizzle: chunk c at slot c^((r>>1)&3) on write (pre-swizzled global
// src) and read (both-sides involution) -> free 2-way.
DI void stageA(const __bf16* __restrict__ A, char* buf, int row0, int k0, int w, int lane) {
#pragma unroll
    for (int o = 0; o < 2; ++o) {
        const int r = o * 64 + w * 16 + (lane >> 2);
        const int cg = (lane & 3) ^ ((r >> 1) & 3);
        async_load16(A + (size_t)(row0 + r) * Dd + k0 + cg * 8, buf + o * 4096 + w * 1024);
    }
}

DI void gemm_core(const __bf16* __restrict__ A, const __bf16* __restrict__ W,
                  char* smem, int row0, int col0, int t, f32x4 acc[4][4]) {
    const int lane = t & 63, w = t >> 6;
    const int l15 = lane & 15, lg = lane >> 4;
    const int wr = (w >> 1) * 64, wc = (w & 1) * 64;

    bfrag b0[4], b1[4];
    auto loadB = [&](int k0, bfrag bq[4]) {
#pragma unroll
        for (int ni = 0; ni < 4; ++ni)
            bq[ni] = *(const bfrag*)(W + (size_t)(col0 + wc + ni * 16 + l15) * Dd + k0 + lg * 8);
    };
    auto readA = [&](const char* buf, bfrag af[4]) {
        const __bf16* Ac = (const __bf16*)buf;
#pragma unroll
        for (int mi = 0; mi < 4; ++mi) {
            const int ra = wr + mi * 16 + l15;
            af[mi] = *(const bfrag*)(Ac + ra * 32 + ((lg ^ ((ra >> 1) & 3)) * 8));
        }
    };
    auto domfma = [&](bfrag af[4], bfrag bq[4]) {
#pragma unroll
        for (int mi = 0; mi < 4; ++mi)
#pragma unroll
            for (int ni = 0; ni < 4; ++ni)
                acc[mi][ni] = __builtin_amdgcn_mfma_f32_16x16x32_bf16(af[mi], bq[ni],
                                                                      acc[mi][ni], 0, 0, 0);
    };

    // prologue
    stageA(A, smem, row0, 0, w, lane);
    loadB(0, b0);
    __syncthreads();

#pragma unroll 1
    for (int kk = 0; kk < 12; ++kk) {
        {   // even step kt = 2kk, A in buf0, B = b0
            const int kt = 2 * kk;
            if (kt < 23) { loadB((kt + 1) * 32, b1); stageA(A, smem + 8192, row0, (kt + 1) * 32, w, lane); }
            bfrag af[4];
            readA(smem, af);
            domfma(af, b0);
            __syncthreads();   // drains vmcnt: next A tile + b1 landed; buf0 reads done
        }
        {   // odd step kt = 2kk+1, A in buf1, B = b1
            const int kt = 2 * kk + 1;
            if (kt < 23) { loadB((kt + 1) * 32, b0); stageA(A, smem, row0, (kt + 1) * 32, w, lane); }
            bfrag af[4];
            readA(smem + 8192, af);
            domfma(af, b1);
            __syncthreads();
        }
    }
}

// ---- fused QKV projection: grid (64, 6, 3), 256 threads ----
// z=0: Q (scaled 0.125*log2e) -> [B,H,S,64]; z=1: K; z=2: V -> V^T [B,H,64,S]
__global__ __launch_bounds__(256) void qkv_gemm(const __bf16* __restrict__ qA, const __bf16* __restrict__ kA,
                                                const __bf16* __restrict__ vA,
                                                const __bf16* __restrict__ qW, const __bf16* __restrict__ kW,
                                                const __bf16* __restrict__ vW,
                                                const float* __restrict__ qb, const float* __restrict__ kb,
                                                const float* __restrict__ vb,
                                                __bf16* __restrict__ qO, __bf16* __restrict__ kO,
                                                __bf16* __restrict__ vO) {
    __shared__ __attribute__((aligned(16))) char smem[34816];  // 16KB A-dbuf; 34816 for V-transpose
    const int z = (int)blockIdx.z;
    const __bf16* A = z == 0 ? qA : z == 1 ? kA : vA;
    const __bf16* W = z == 0 ? qW : z == 1 ? kW : vW;
    const float* bias = z == 0 ? qb : z == 1 ? kb : vb;
    __bf16* O = z == 0 ? qO : z == 1 ? kO : vO;

    const int t = (int)threadIdx.x;
    const int lane = t & 63, w = t >> 6;
    const int l15 = lane & 15, lg = lane >> 4;
    const int row0 = (int)blockIdx.x * 128, col0 = (int)blockIdx.y * 128;
    const int wr = (w >> 1) * 64, wc = (w & 1) * 64;

    f32x4 acc[4][4] = {};
    gemm_core(A, W, smem, row0, col0, t, acc);

    if (z == 2) {
        // transpose epilogue: acc -> LDS T[128 d][136 pad s] -> coalesced V^T write
        __syncthreads();
        auto T = reinterpret_cast<__bf16(*)[136]>(smem);
#pragma unroll
        for (int mi = 0; mi < 4; ++mi) {
#pragma unroll
            for (int ni = 0; ni < 4; ++ni) {
                const float bv = bias[col0 + wc + ni * 16 + l15];
#pragma unroll
                for (int j = 0; j < 4; ++j)
                    T[wc + ni * 16 + l15][wr + mi * 16 + lg * 4 + j] = (__bf16)(acc[mi][ni][j] + bv);
            }
        }
        __syncthreads();
        const int bb2 = row0 >> 10, sb = row0 & 1023;
#pragma unroll
        for (int i = 0; i < 8; ++i) {
            const int ld = i * 16 + (t >> 4);   // local d 0..127
            const int ck = (t & 15) * 8;        // s-chunk offset
            const int head = (col0 + ld) >> 6, dd = (col0 + ld) & 63;
            __bf16* dst = O + ((size_t)(bb2 * Hh + head) * DKk + dd) * Ss + sb + ck;
            *reinterpret_cast<bfrag*>(dst) = *reinterpret_cast<const bfrag*>(&T[ld][ck]);
        }
    } else {
        const float scl = (z == 0) ? 0.18033688f : 1.0f;  // 0.125 * log2(e)
#pragma unroll
        for (int mi = 0; mi < 4; ++mi) {
#pragma unroll
            for (int ni = 0; ni < 4; ++ni) {
                const int cg = col0 + wc + ni * 16 + l15;
                const float bv = bias[cg];
#pragma unroll
                for (int j = 0; j < 4; ++j) {
                    const int rg = row0 + wr + mi * 16 + lg * 4 + j;
                    const float val = (acc[mi][ni][j] + bv) * scl;
                    const int bb = rg >> 10, ss = rg & 1023;
                    const int hh2 = cg >> 6, dd = cg & 63;
                    O[((size_t)(bb * Hh + hh2) * Ss + ss) * DKk + dd] = (__bf16)val;
                }
            }
        }
    }
}

// ---- output projection: bf16 A [M][768] x bf16 Wo -> fp32 [M][768] + bias ----
__global__ __launch_bounds__(256) void o_gemm(const __bf16* __restrict__ A, const __bf16* __restrict__ W,
                                              const float* __restrict__ bias, float* __restrict__ Out) {
    __shared__ __attribute__((aligned(16))) char smem[16384];
    const int t = (int)threadIdx.x;
    const int lane = t & 63, w = t >> 6;
    const int l15 = lane & 15, lg = lane >> 4;
    const int row0 = (int)blockIdx.x * 128, col0 = (int)blockIdx.y * 128;
    const int wr = (w >> 1) * 64, wc = (w & 1) * 64;

    f32x4 acc[4][4] = {};
    gemm_core(A, W, smem, row0, col0, t, acc);

#pragma unroll
    for (int mi = 0; mi < 4; ++mi) {
#pragma unroll
        for (int ni = 0; ni < 4; ++ni) {
            const int cg = col0 + wc + ni * 16 + l15;
            const float bv = bias[cg];
#pragma unroll
            for (int j = 0; j < 4; ++j) {
                const int rg = row0 + wr + mi * 16 + lg * 4 + j;
                Out[(size_t)rg * Dd + cg] = acc[mi][ni][j] + bv;
            }
        }
    }
}

// ---- Flash attention (unchanged): QBLK=64, NO-MAX base-2 softmax,
// T14 async-STAGE split + T5 setprio. 1536 blocks, 96-bijective XCD grouping. ----
__global__ __launch_bounds__(256) void attn_k(const __bf16* __restrict__ q,
                                              const __bf16* __restrict__ k,
                                              const __bf16* __restrict__ vt,
                                              __bf16* __restrict__ o) {
    __shared__ __attribute__((aligned(16))) __bf16 Ks[64][72];
    __shared__ __attribute__((aligned(16))) __bf16 Vs[64][72];
    __shared__ __attribute__((aligned(16))) __bf16 plds[4][16][72];
    const int t = (int)threadIdx.x;
    const int lane = t & 63, w = t >> 6;
    const int l15 = lane & 15, lg = lane >> 4;
    const int blk = (int)blockIdx.x;
    const int bh = blk % 96, qt = blk / 96;
    const size_t bhb = (size_t)bh * Ss;
    const __bf16* qp = q + bhb * DKk;
    const __bf16* kp = k + bhb * DKk;
    const __bf16* vtp = vt + bhb * DKk;
    const int qbase = qt * 64 + w * 16;
    const int srow = t >> 2, sc = (t & 3) * 16;

    bfrag bq[2];
#pragma unroll
    for (int ks = 0; ks < 2; ++ks)
        bq[ks] = *reinterpret_cast<const bfrag*>(qp + (size_t)(qbase + l15) * DKk + ks * 32 + lg * 8);

    float lrow = 0.f;
    f32x4 oacc[4] = {};

    {
        bfrag k0a = *reinterpret_cast<const bfrag*>(kp + (size_t)srow * DKk + sc);
        bfrag k0b = *reinterpret_cast<const bfrag*>(kp + (size_t)srow * DKk + sc + 8);
        bfrag v0a = *reinterpret_cast<const bfrag*>(vtp + (size_t)srow * Ss + sc);
        bfrag v0b = *reinterpret_cast<const bfrag*>(vtp + (size_t)srow * Ss + sc + 8);
        *reinterpret_cast<bfrag*>(&Ks[srow][sc]) = k0a;
        *reinterpret_cast<bfrag*>(&Ks[srow][sc + 8]) = k0b;
        *reinterpret_cast<bfrag*>(&Vs[srow][sc]) = v0a;
        *reinterpret_cast<bfrag*>(&Vs[srow][sc + 8]) = v0b;
    }
    __syncthreads();

    for (int kt = 0; kt < 16; ++kt) {
        bfrag kna, knb, vna, vnb;
        if (kt < 15) {
            const int kb1 = (kt + 1) * 64;
            kna = *reinterpret_cast<const bfrag*>(kp + (size_t)(kb1 + srow) * DKk + sc);
            knb = *reinterpret_cast<const bfrag*>(kp + (size_t)(kb1 + srow) * DKk + sc + 8);
            vna = *reinterpret_cast<const bfrag*>(vtp + (size_t)srow * Ss + kb1 + sc);
            vnb = *reinterpret_cast<const bfrag*>(vtp + (size_t)srow * Ss + kb1 + sc + 8);
        }

        f32x4 sacc[4] = {};
        __builtin_amdgcn_s_setprio(1);
#pragma unroll
        for (int n = 0; n < 4; ++n) {
#pragma unroll
            for (int ks = 0; ks < 2; ++ks) {
                const bfrag ak = *reinterpret_cast<const bfrag*>(&Ks[n * 16 + l15][ks * 32 + lg * 8]);
                sacc[n] = __builtin_amdgcn_mfma_f32_16x16x32_bf16(ak, bq[ks], sacc[n], 0, 0, 0);
            }
        }
        __builtin_amdgcn_s_setprio(0);

        float p[4][4];
        float rs = 0.f;
#pragma unroll
        for (int n = 0; n < 4; ++n)
#pragma unroll
            for (int j = 0; j < 4; ++j) {
                const float pe = EXP2(sacc[n][j]);
                p[n][j] = pe;
                rs += pe;
            }
        rs += __shfl_xor(rs, 16);
        rs += __shfl_xor(rs, 32);
        lrow += rs;

#pragma unroll
        for (int n = 0; n < 4; ++n) {
            bf16x4 pk;
#pragma unroll
            for (int j = 0; j < 4; ++j) pk[j] = (__bf16)p[n][j];
            *reinterpret_cast<bf16x4*>(&plds[w][l15][n * 16 + lg * 4]) = pk;
        }

        __builtin_amdgcn_s_setprio(1);
#pragma unroll
        for (int ks = 0; ks < 2; ++ks) {
            const bfrag ap = *reinterpret_cast<const bfrag*>(&plds[w][l15][ks * 32 + lg * 8]);
#pragma unroll
            for (int dt = 0; dt < 4; ++dt) {
                const bfrag bv = *reinterpret_cast<const bfrag*>(&Vs[dt * 16 + l15][ks * 32 + lg * 8]);
                oacc[dt] = __builtin_amdgcn_mfma_f32_16x16x32_bf16(ap, bv, oacc[dt], 0, 0, 0);
            }
        }
        __builtin_amdgcn_s_setprio(0);

        __syncthreads();
        if (kt < 15) {
            *reinterpret_cast<bfrag*>(&Ks[srow][sc]) = kna;
            *reinterpret_cast<bfrag*>(&Ks[srow][sc + 8]) = knb;
            *reinterpret_cast<bfrag*>(&Vs[srow][sc]) = vna;
            *reinterpret_cast<bfrag*>(&Vs[srow][sc + 8]) = vnb;
        }
        __syncthreads();
    }

    float linv[4];
#pragma unroll
    for (int j = 0; j < 4; ++j) linv[j] = 1.0f / __shfl(lrow, lg * 4 + j);
    const int bb = bh / Hh, hh = bh % Hh;
#pragma unroll
    for (int dt = 0; dt < 4; ++dt)
#pragma unroll
        for (int j = 0; j < 4; ++j) {
            const int qrow = qbase + lg * 4 + j;
            o[((size_t)(bb * Ss + qrow)) * Dd + hh * DKk + dt * 16 + l15] =
                (__bf16)(oacc[dt][j] * linv[j]);
        }
}

extern "C" void kernel_launch(void* const* d_in, const int* in_sizes, int n_in,
                              void* d_out, int out_size, void* d_ws, size_t ws_size,
                              hipStream_t stream) {
    (void)in_sizes; (void)n_in; (void)out_size; (void)ws_size;
    // dict order: key, query, value, Wk, bk, Wq, bq, Wv, bv, Wo, bo
    const float* key   = (const float*)d_in[0];
    const float* query = (const float*)d_in[1];
    const float* value = (const float*)d_in[2];
    const float* Wk = (const float*)d_in[3];
    const float* bk = (const float*)d_in[4];
    const float* Wq = (const float*)d_in[5];
    const float* bq = (const float*)d_in[6];
    const float* Wv = (const float*)d_in[7];
    const float* bvp = (const float*)d_in[8];
    const float* Wo = (const float*)d_in[9];
    const float* bo = (const float*)d_in[10];

    const size_t NA = (size_t)Mm * Dd;   // 6291456 activation elems
    const size_t NW = (size_t)Dd * Dd;   // 589824 weight elems
    __bf16* p = (__bf16*)d_ws;
    __bf16* qab = p;            p += NA;   // bf16 query
    __bf16* kab = p;            p += NA;   // bf16 key
    __bf16* vab = p;            p += NA;   // bf16 value
    __bf16* wqb = p;            p += NW;
    __bf16* wkb = p;            p += NW;
    __bf16* wvb = p;            p += NW;
    __bf16* wob = p;            p += NW;
    __bf16* qws = p;            p += NA;   // Q proj (scaled by 0.125*log2e)
    __bf16* kws = p;            p += NA;   // K proj
    __bf16* vtws = p;           p += NA;   // V^T proj
    __bf16* aws = qab;                     // attn out aliases dead qab

    dim3 blk(256);
    cvt_k<<<dim3(10368), blk, 0, stream>>>(query, key, value, Wq, Wk, Wv, Wo,
                                           qab, kab, vab, wqb, wkb, wvb, wob);
    qkv_gemm<<<dim3(Mm / 128, Dd / 128, 3), blk, 0, stream>>>(qab, kab, vab,
                                                              wqb, wkb, wvb,
                                                              bq, bk, bvp,
                                                              qws, kws, vtws);
    attn_k<<<dim3(Ss / 64 * Hh * Bb), blk, 0, stream>>>(qws, kws, vtws, aws);
    o_gemm<<<dim3(Mm / 128, Dd / 128), blk, 0, stream>>>(aws, wob, bo, (float*)d_out);
}

// Round 15
// 136.365 us; speedup vs baseline: 1.2838x; 1.2838x over previous
//
#include <hip/hip_runtime.h>
#include <stdint.h>

#define DI __device__ __forceinline__

typedef __attribute__((ext_vector_type(8))) __bf16 bfrag;   // MFMA A/B operand (4 VGPRs)
typedef __attribute__((ext_vector_type(4))) __bf16 bf16x4;
typedef __attribute__((ext_vector_type(4))) float f32x4;    // MFMA C/D operand

static constexpr int Bb = 8, Ss = 1024, Dd = 768, Hh = 12, DKk = 64;
static constexpr int Mm = Bb * Ss;          // 8192 rows

typedef __attribute__((address_space(3))) void lds_void_t;
typedef const __attribute__((address_space(1))) void gvoid_t;

DI void async_load16(const void* g, void* lds) {
    __builtin_amdgcn_global_load_lds((gvoid_t*)(uintptr_t)g,
                                     (lds_void_t*)(uint32_t)(uintptr_t)lds, 16, 0, 0);
}

#if __has_builtin(__builtin_amdgcn_exp2f)
#define EXP2(x) __builtin_amdgcn_exp2f(x)
#else
extern "C" __device__ float __ocml_exp2_f32(float);
#define EXP2(x) __ocml_exp2_f32(x)
#endif

// ---- fp32 -> bf16 convert, all 7 tensors in ONE launch ----
// blocks 0..9215: activations (3 x 3072); 9216..10367: weights (4 x 288)
__global__ __launch_bounds__(256) void cvt_k(const float* __restrict__ a0, const float* __restrict__ a1,
                                             const float* __restrict__ a2,
                                             const float* __restrict__ w0, const float* __restrict__ w1,
                                             const float* __restrict__ w2, const float* __restrict__ w3,
                                             __bf16* __restrict__ da0, __bf16* __restrict__ da1,
                                             __bf16* __restrict__ da2,
                                             __bf16* __restrict__ dw0, __bf16* __restrict__ dw1,
                                             __bf16* __restrict__ dw2, __bf16* __restrict__ dw3) {
    const int bid = (int)blockIdx.x;
    const float* s; __bf16* d; int off;
    if (bid < 9216) {
        const int ti = bid / 3072;
        off = (bid % 3072) * 2048;
        s = ti == 0 ? a0 : ti == 1 ? a1 : a2;
        d = ti == 0 ? da0 : ti == 1 ? da1 : da2;
    } else {
        const int b2 = bid - 9216;
        const int ti = b2 / 288;
        off = (b2 % 288) * 2048;
        s = ti == 0 ? w0 : ti == 1 ? w1 : ti == 2 ? w2 : w3;
        d = ti == 0 ? dw0 : ti == 1 ? dw1 : ti == 2 ? dw2 : dw3;
    }
    const int i = off + (int)threadIdx.x * 8;
    f32x4 a = *(const f32x4*)(s + i);
    f32x4 b = *(const f32x4*)(s + i + 4);
    bfrag o;
#pragma unroll
    for (int j = 0; j < 4; ++j) { o[j] = (__bf16)a[j]; o[j + 4] = (__bf16)b[j]; }
    *(bfrag*)(d + i) = o;
}

// ---- GEMM core (r8-measured best for this shape): 128x128 tile, BK=64,
// global_load_lds w16 staging into swizzled linear LDS, 2-barrier K-loop.
// LDS elem (r, chunk c_glob of 8) at byte r*128 + (c_glob ^ (r&7))*16.
DI void gemm_core(const __bf16* __restrict__ A, const __bf16* __restrict__ W,
                  __bf16* As, __bf16* Bs, int row0, int col0, int t, f32x4 acc[4][4]) {
    const int lane = t & 63, w = t >> 6;
    const int l15 = lane & 15, lg = lane >> 4;
    const int wr = (w >> 1) * 64, wc = (w & 1) * 64;
    const int rl = lane >> 3, clin = lane & 7;   // staging: row-in-op, linear chunk

    for (int k0 = 0; k0 < 768; k0 += 64) {
        __syncthreads();   // all waves done reading previous tile
#pragma unroll
        for (int o = 0; o < 4; ++o) {
            const int g = w * 4 + o;           // op id 0..15, wave-uniform
            const int r = g * 8 + rl;          // tile row 0..127
            const int cg = clin ^ (r & 7);     // pre-swizzled global chunk
            async_load16(A + (size_t)(row0 + r) * Dd + k0 + cg * 8, As + g * 512);
            async_load16(W + (size_t)(col0 + r) * Dd + k0 + cg * 8, Bs + g * 512);
        }
        __syncthreads();   // compiler drains vmcnt before barrier -> LDS visible

        bfrag af[4][2], bf[4][2];
#pragma unroll
        for (int mi = 0; mi < 4; ++mi) {
            const int ra = wr + mi * 16 + l15;
            const int rb = wc + mi * 16 + l15;
#pragma unroll
            for (int ks = 0; ks < 2; ++ks) {
                af[mi][ks] = *(const bfrag*)(As + ra * 64 + (((ks * 4 + lg) ^ (ra & 7)) * 8));
                bf[mi][ks] = *(const bfrag*)(Bs + rb * 64 + (((ks * 4 + lg) ^ (rb & 7)) * 8));
            }
        }
#pragma unroll
        for (int mi = 0; mi < 4; ++mi)
#pragma unroll
            for (int ni = 0; ni < 4; ++ni)
#pragma unroll
                for (int ks = 0; ks < 2; ++ks)
                    acc[mi][ni] = __builtin_amdgcn_mfma_f32_16x16x32_bf16(af[mi][ks], bf[ni][ks],
                                                                          acc[mi][ni], 0, 0, 0);
    }
}

// ---- fused QKV projection: 1-D grid 1152, T1 XCD-bijective swizzle ----
// logical l = (h&7)*144 + h/8  (1152%8==0, bijective). l = z*384 + x*6 + y
// (y fastest) -> each XCD owns 24 contiguous A-row-panels of one tensor
// (24 x 192KB = 4.6MB ~ L2), each reused by its 6 N-tiles locally.
// z=0: Q (scaled 0.125*log2e) -> [B,H,S,64]; z=1: K; z=2: V -> V^T [B,H,64,S]
__global__ __launch_bounds__(256) void qkv_gemm(const __bf16* __restrict__ qA, const __bf16* __restrict__ kA,
                                                const __bf16* __restrict__ vA,
                                                const __bf16* __restrict__ qW, const __bf16* __restrict__ kW,
                                                const __bf16* __restrict__ vW,
                                                const float* __restrict__ qb, const float* __restrict__ kb,
                                                const float* __restrict__ vb,
                                                __bf16* __restrict__ qO, __bf16* __restrict__ kO,
                                                __bf16* __restrict__ vO) {
    __shared__ __attribute__((aligned(16))) char smem[34816];  // 32KB staging; 34816 for V-transpose
    __bf16* As = (__bf16*)smem;
    __bf16* Bs = (__bf16*)(smem + 16384);

    const int h = (int)blockIdx.x;
    const int l = (h & 7) * 144 + (h >> 3);
    const int z = l / 384, r2 = l % 384;
    const int row0 = (r2 / 6) * 128, col0 = (r2 % 6) * 128;

    const __bf16* A = z == 0 ? qA : z == 1 ? kA : vA;
    const __bf16* W = z == 0 ? qW : z == 1 ? kW : vW;
    const float* bias = z == 0 ? qb : z == 1 ? kb : vb;
    __bf16* O = z == 0 ? qO : z == 1 ? kO : vO;

    const int t = (int)threadIdx.x;
    const int lane = t & 63, w = t >> 6;
    const int l15 = lane & 15, lg = lane >> 4;
    const int wr = (w >> 1) * 64, wc = (w & 1) * 64;

    f32x4 acc[4][4] = {};
    gemm_core(A, W, As, Bs, row0, col0, t, acc);

    if (z == 2) {
        // transpose epilogue: acc -> LDS T[128 d][136 pad s] -> coalesced V^T write
        __syncthreads();
        auto T = reinterpret_cast<__bf16(*)[136]>(smem);
#pragma unroll
        for (int mi = 0; mi < 4; ++mi) {
#pragma unroll
            for (int ni = 0; ni < 4; ++ni) {
                const float bv = bias[col0 + wc + ni * 16 + l15];
#pragma unroll
                for (int j = 0; j < 4; ++j)
                    T[wc + ni * 16 + l15][wr + mi * 16 + lg * 4 + j] = (__bf16)(acc[mi][ni][j] + bv);
            }
        }
        __syncthreads();
        const int bb2 = row0 >> 10, sb = row0 & 1023;
#pragma unroll
        for (int i = 0; i < 8; ++i) {
            const int ld = i * 16 + (t >> 4);   // local d 0..127
            const int ck = (t & 15) * 8;        // s-chunk offset
            const int head = (col0 + ld) >> 6, dd = (col0 + ld) & 63;
            __bf16* dst = O + ((size_t)(bb2 * Hh + head) * DKk + dd) * Ss + sb + ck;
            *reinterpret_cast<bfrag*>(dst) = *reinterpret_cast<const bfrag*>(&T[ld][ck]);
        }
    } else {
        const float scl = (z == 0) ? 0.18033688f : 1.0f;  // 0.125 * log2(e)
#pragma unroll
        for (int mi = 0; mi < 4; ++mi) {
#pragma unroll
            for (int ni = 0; ni < 4; ++ni) {
                const int cg = col0 + wc + ni * 16 + l15;
                const float bv = bias[cg];
#pragma unroll
                for (int j = 0; j < 4; ++j) {
                    const int rg = row0 + wr + mi * 16 + lg * 4 + j;
                    const float val = (acc[mi][ni][j] + bv) * scl;
                    const int bb = rg >> 10, ss = rg & 1023;
                    const int hh2 = cg >> 6, dd = cg & 63;
                    O[((size_t)(bb * Hh + hh2) * Ss + ss) * DKk + dd] = (__bf16)val;
                }
            }
        }
    }
}

// ---- output projection: 1-D grid 384, same T1 swizzle (384%8==0, x48) ----
__global__ __launch_bounds__(256) void o_gemm(const __bf16* __restrict__ A, const __bf16* __restrict__ W,
                                              const float* __restrict__ bias, float* __restrict__ Out) {
    __shared__ __attribute__((aligned(16))) char smem[32768];
    __bf16* As = (__bf16*)smem;
    __bf16* Bs = (__bf16*)(smem + 16384);

    const int h = (int)blockIdx.x;
    const int l = (h & 7) * 48 + (h >> 3);
    const int row0 = (l / 6) * 128, col0 = (l % 6) * 128;

    const int t = (int)threadIdx.x;
    const int lane = t & 63, w = t >> 6;
    const int l15 = lane & 15, lg = lane >> 4;
    const int wr = (w >> 1) * 64, wc = (w & 1) * 64;

    f32x4 acc[4][4] = {};
    gemm_core(A, W, As, Bs, row0, col0, t, acc);

#pragma unroll
    for (int mi = 0; mi < 4; ++mi) {
#pragma unroll
        for (int ni = 0; ni < 4; ++ni) {
            const int cg = col0 + wc + ni * 16 + l15;
            const float bv = bias[cg];
#pragma unroll
            for (int j = 0; j < 4; ++j) {
                const int rg = row0 + wr + mi * 16 + lg * 4 + j;
                Out[(size_t)rg * Dd + cg] = acc[mi][ni][j] + bv;
            }
        }
    }
}

// ---- Flash attention (r8-measured): QBLK=64, NO-MAX base-2 softmax,
// T14 async-STAGE split + T5 setprio. 1536 blocks, 96-bijective XCD grouping. ----
__global__ __launch_bounds__(256) void attn_k(const __bf16* __restrict__ q,
                                              const __bf16* __restrict__ k,
                                              const __bf16* __restrict__ vt,
                                              __bf16* __restrict__ o) {
    __shared__ __attribute__((aligned(16))) __bf16 Ks[64][72];   // [key][d]
    __shared__ __attribute__((aligned(16))) __bf16 Vs[64][72];   // [d][key]
    __shared__ __attribute__((aligned(16))) __bf16 plds[4][16][72];
    const int t = (int)threadIdx.x;
    const int lane = t & 63, w = t >> 6;
    const int l15 = lane & 15, lg = lane >> 4;
    const int blk = (int)blockIdx.x;
    const int bh = blk % 96, qt = blk / 96;   // 96 % 8 == 0: bijective XCD grouping
    const size_t bhb = (size_t)bh * Ss;
    const __bf16* qp = q + bhb * DKk;
    const __bf16* kp = k + bhb * DKk;
    const __bf16* vtp = vt + bhb * DKk;  // V^T: [64 d][1024 s]
    const int qbase = qt * 64 + w * 16;
    const int srow = t >> 2, sc = (t & 3) * 16;

    bfrag bq[2];
#pragma unroll
    for (int ks = 0; ks < 2; ++ks)
        bq[ks] = *reinterpret_cast<const bfrag*>(qp + (size_t)(qbase + l15) * DKk + ks * 32 + lg * 8);

    float lrow = 0.f;            // per-lane denom for q = l15 (replicated over lg)
    f32x4 oacc[4] = {};

    {   // prologue: stage tile 0
        bfrag k0a = *reinterpret_cast<const bfrag*>(kp + (size_t)srow * DKk + sc);
        bfrag k0b = *reinterpret_cast<const bfrag*>(kp + (size_t)srow * DKk + sc + 8);
        bfrag v0a = *reinterpret_cast<const bfrag*>(vtp + (size_t)srow * Ss + sc);
        bfrag v0b = *reinterpret_cast<const bfrag*>(vtp + (size_t)srow * Ss + sc + 8);
        *reinterpret_cast<bfrag*>(&Ks[srow][sc]) = k0a;
        *reinterpret_cast<bfrag*>(&Ks[srow][sc + 8]) = k0b;
        *reinterpret_cast<bfrag*>(&Vs[srow][sc]) = v0a;
        *reinterpret_cast<bfrag*>(&Vs[srow][sc + 8]) = v0b;
    }
    __syncthreads();

    for (int kt = 0; kt < 16; ++kt) {
        // T14: issue next tile's global loads BEFORE compute; write after barrier
        bfrag kna, knb, vna, vnb;
        if (kt < 15) {
            const int kb1 = (kt + 1) * 64;
            kna = *reinterpret_cast<const bfrag*>(kp + (size_t)(kb1 + srow) * DKk + sc);
            knb = *reinterpret_cast<const bfrag*>(kp + (size_t)(kb1 + srow) * DKk + sc + 8);
            vna = *reinterpret_cast<const bfrag*>(vtp + (size_t)srow * Ss + kb1 + sc);
            vnb = *reinterpret_cast<const bfrag*>(vtp + (size_t)srow * Ss + kb1 + sc + 8);
        }

        // QK^T swapped: A = K rows (key), B = Q cols (q). sacc[n][j]: key = n*16+lg*4+j, q = l15
        f32x4 sacc[4] = {};
        __builtin_amdgcn_s_setprio(1);
#pragma unroll
        for (int n = 0; n < 4; ++n) {
#pragma unroll
            for (int ks = 0; ks < 2; ++ks) {
                const bfrag ak = *reinterpret_cast<const bfrag*>(&Ks[n * 16 + l15][ks * 32 + lg * 8]);
                sacc[n] = __builtin_amdgcn_mfma_f32_16x16x32_bf16(ak, bq[ks], sacc[n], 0, 0, 0);
            }
        }
        __builtin_amdgcn_s_setprio(0);

        // no-max softmax: p = exp2(s) (Q pre-scaled by 0.125*log2e), accumulate denom
        float p[4][4];
        float rs = 0.f;
#pragma unroll
        for (int n = 0; n < 4; ++n)
#pragma unroll
            for (int j = 0; j < 4; ++j) {
                const float pe = EXP2(sacc[n][j]);
                p[n][j] = pe;
                rs += pe;
            }
        rs += __shfl_xor(rs, 16);
        rs += __shfl_xor(rs, 32);
        lrow += rs;

        // P -> wave-private LDS, packed b64: row = q = l15, keys n*16+lg*4+{0..3}
#pragma unroll
        for (int n = 0; n < 4; ++n) {
            bf16x4 pk;
#pragma unroll
            for (int j = 0; j < 4; ++j) pk[j] = (__bf16)p[n][j];
            *reinterpret_cast<bf16x4*>(&plds[w][l15][n * 16 + lg * 4]) = pk;
        }

        // PV: A = P (row = q = l15, k = key), B = V^T tile in LDS (col = d = l15)
        __builtin_amdgcn_s_setprio(1);
#pragma unroll
        for (int ks = 0; ks < 2; ++ks) {
            const bfrag ap = *reinterpret_cast<const bfrag*>(&plds[w][l15][ks * 32 + lg * 8]);
#pragma unroll
            for (int dt = 0; dt < 4; ++dt) {
                const bfrag bv = *reinterpret_cast<const bfrag*>(&Vs[dt * 16 + l15][ks * 32 + lg * 8]);
                oacc[dt] = __builtin_amdgcn_mfma_f32_16x16x32_bf16(ap, bv, oacc[dt], 0, 0, 0);
            }
        }
        __builtin_amdgcn_s_setprio(0);

        __syncthreads();  // all waves done reading Ks/Vs
        if (kt < 15) {
            *reinterpret_cast<bfrag*>(&Ks[srow][sc]) = kna;
            *reinterpret_cast<bfrag*>(&Ks[srow][sc + 8]) = knb;
            *reinterpret_cast<bfrag*>(&Vs[srow][sc]) = vna;
            *reinterpret_cast<bfrag*>(&Vs[srow][sc + 8]) = vnb;
        }
        __syncthreads();  // writes visible
    }

    // epilogue: divide by l for q = lg*4+j (held by lane lg*4+j), write [B,S,D]
    float linv[4];
#pragma unroll
    for (int j = 0; j < 4; ++j) linv[j] = 1.0f / __shfl(lrow, lg * 4 + j);
    const int bb = bh / Hh, hh = bh % Hh;
#pragma unroll
    for (int dt = 0; dt < 4; ++dt)
#pragma unroll
        for (int j = 0; j < 4; ++j) {
            const int qrow = qbase + lg * 4 + j;
            o[((size_t)(bb * Ss + qrow)) * Dd + hh * DKk + dt * 16 + l15] =
                (__bf16)(oacc[dt][j] * linv[j]);
        }
}

extern "C" void kernel_launch(void* const* d_in, const int* in_sizes, int n_in,
                              void* d_out, int out_size, void* d_ws, size_t ws_size,
                              hipStream_t stream) {
    (void)in_sizes; (void)n_in; (void)out_size; (void)ws_size;
    // dict order: key, query, value, Wk, bk, Wq, bq, Wv, bv, Wo, bo
    const float* key   = (const float*)d_in[0];
    const float* query = (const float*)d_in[1];
    const float* value = (const float*)d_in[2];
    const float* Wk = (const float*)d_in[3];
    const float* bk = (const float*)d_in[4];
    const float* Wq = (const float*)d_in[5];
    const float* bq = (const float*)d_in[6];
    const float* Wv = (const float*)d_in[7];
    const float* bvp = (const float*)d_in[8];
    const float* Wo = (const float*)d_in[9];
    const float* bo = (const float*)d_in[10];

    const size_t NA = (size_t)Mm * Dd;   // 6291456 activation elems
    const size_t NW = (size_t)Dd * Dd;   // 589824 weight elems
    __bf16* p = (__bf16*)d_ws;
    __bf16* qab = p;            p += NA;   // bf16 query
    __bf16* kab = p;            p += NA;   // bf16 key
    __bf16* vab = p;            p += NA;   // bf16 value
    __bf16* wqb = p;            p += NW;
    __bf16* wkb = p;            p += NW;
    __bf16* wvb = p;            p += NW;
    __bf16* wob = p;            p += NW;
    __bf16* qws = p;            p += NA;   // Q proj (scaled by 0.125*log2e)
    __bf16* kws = p;            p += NA;   // K proj
    __bf16* vtws = p;           p += NA;   // V^T proj
    __bf16* aws = qab;                     // attn out aliases dead qab

    dim3 blk(256);
    cvt_k<<<dim3(10368), blk, 0, stream>>>(query, key, value, Wq, Wk, Wv, Wo,
                                           qab, kab, vab, wqb, wkb, wvb, wob);
    qkv_gemm<<<dim3(1152), blk, 0, stream>>>(qab, kab, vab,
                                             wqb, wkb, wvb,
                                             bq, bk, bvp,
                                             qws, kws, vtws);
    attn_k<<<dim3(Ss / 64 * Hh * Bb), blk, 0, stream>>>(qws, kws, vtws, aws);
    o_gemm<<<dim3(384), blk, 0, stream>>>(aws, wob, bo, (float*)d_out);
}